// Round 3
// baseline (202.764 us; speedup 1.0000x reference)
//
#include <hip/hip_runtime.h>
#include <stdint.h>

typedef unsigned short u16;
typedef __attribute__((ext_vector_type(8))) short bf16x8;
typedef __attribute__((ext_vector_type(4))) float f32x4;

__device__ __forceinline__ u16 f2bf(float f){
  union { float f; uint32_t u; } v; v.f = f;
  uint32_t u = v.u;
  u += 0x7FFFu + ((u >> 16) & 1u);
  return (u16)(u >> 16);
}

__device__ __forceinline__ float fexp2(float x){
#if __has_builtin(__builtin_amdgcn_exp2f)
  return __builtin_amdgcn_exp2f(x);
#else
  return exp2f(x);
#endif
}

__device__ __forceinline__ uint32_t cvtpk_bf16(float lo, float hi){
  uint32_t d;
  asm("v_cvt_pk_bf16_f32 %0, %1, %2" : "=v"(d) : "v"(lo), "v"(hi));
  return d;
}

__device__ __forceinline__ f32x4 mfma_bf16(bf16x8 a, bf16x8 b, f32x4 c){
  return __builtin_amdgcn_mfma_f32_16x16x32_bf16(a, b, c, 0, 0, 0);
}

// 0.125 (1/sqrt(64)) * log2(e) -- folded into Q at the QKV epilogue
#define QSCALE 0.1803368801111244f

// ---------------- cast x (fp32 -> bf16), 4 elems/thread ----------------
__global__ __launch_bounds__(256) void cast_x_k(const float* __restrict__ x,
                                                u16* __restrict__ xb, int n4){
  int i = blockIdx.x*256 + threadIdx.x;
  if (i >= n4) return;
  float4 v = reinterpret_cast<const float4*>(x)[i];
  uint2 o;
  o.x = (uint32_t)f2bf(v.x) | ((uint32_t)f2bf(v.y) << 16);
  o.y = (uint32_t)f2bf(v.z) | ((uint32_t)f2bf(v.w) << 16);
  reinterpret_cast<uint2*>(xb)[i] = o;
}

// ---------------- transpose+cast: fp32 [R][C] -> bf16 [C][R] ----------------
__global__ __launch_bounds__(256) void transpose_cast_k(const float* __restrict__ in,
                                                        u16* __restrict__ out,
                                                        int R, int C){
  __shared__ u16 tile[64][66];
  int c0 = blockIdx.x*64, r0 = blockIdx.y*64;
  int tc = threadIdx.x & 63, t4 = threadIdx.x >> 6;
  #pragma unroll
  for (int i=0;i<16;i++){ int r = t4 + i*4; tile[r][tc] = f2bf(in[(size_t)(r0+r)*C + c0 + tc]); }
  __syncthreads();
  #pragma unroll
  for (int i=0;i<16;i++){ int cc = t4 + i*4; out[(size_t)(c0+cc)*R + r0 + tc] = tile[tc][cc]; }
}

// ---------------- bf16 MFMA GEMM: C[M][N] = A[M][K] * Bt[N][K]^T + bias ----------------
// mode 0: fp32 out to fo.
// mode 1: scatter bf16: q (pre-scaled) and k into [B*H][T][64]; v written TRANSPOSED
//         into [B*H][64][T] (feeds the PV step directly, kills the transpose kernel).
#define LDP 40   // padded LDS row stride (shorts)

__global__ __launch_bounds__(256) void gemm_bf16_k(
    const u16* __restrict__ A, const u16* __restrict__ Bt,
    int M, int N, int K, const float* __restrict__ bias, int mode,
    u16* __restrict__ qo, u16* __restrict__ ko, u16* __restrict__ vo,
    float* __restrict__ fo)
{
  __shared__ u16 As[128*LDP];
  __shared__ u16 Bs[128*LDP];
  const int m0 = blockIdx.y*128, n0 = blockIdx.x*128;
  const int tid = threadIdx.x, lane = tid & 63, wid = tid >> 6;
  const int lr = lane & 15, lg = lane >> 4;
  const int wr = wid >> 1, wc = wid & 1;
  f32x4 acc[4][4] = {};
  const int nk = K >> 5;
  for (int kk = 0; kk < nk; ++kk){
    #pragma unroll
    for (int s = 0; s < 2; ++s){
      int ci = tid + 256*s;
      int row = ci >> 2, ch = ci & 3;
      *(uint4*)&As[row*LDP + ch*8] = *(const uint4*)&A[(size_t)(m0+row)*K + kk*32 + ch*8];
      *(uint4*)&Bs[row*LDP + ch*8] = *(const uint4*)&Bt[(size_t)(n0+row)*K + kk*32 + ch*8];
    }
    __syncthreads();
    bf16x8 af[4], bfr[4];
    #pragma unroll
    for (int m=0;m<4;m++) af[m] = *(const bf16x8*)&As[(wr*64 + m*16 + lr)*LDP + lg*8];
    #pragma unroll
    for (int n=0;n<4;n++) bfr[n] = *(const bf16x8*)&Bs[(wc*64 + n*16 + lr)*LDP + lg*8];
    #pragma unroll
    for (int m=0;m<4;m++)
      #pragma unroll
      for (int n=0;n<4;n++)
        acc[m][n] = mfma_bf16(af[m], bfr[n], acc[m][n]);
    __syncthreads();
  }
  if (mode == 0){
    #pragma unroll
    for (int m=0;m<4;m++)
      #pragma unroll
      for (int n=0;n<4;n++){
        int gn = n0 + wc*64 + n*16 + lr;
        float bv = bias[gn];
        #pragma unroll
        for (int r=0;r<4;r++){
          int gm = m0 + wr*64 + m*16 + lg*4 + r;
          fo[(size_t)gm*N + gn] = acc[m][n][r] + bv;
        }
      }
  } else {
    int which = n0 / 768;               // 0=q 1=k 2=v, uniform per block
    u16* dst = (which==0) ? qo : ko;
    float sc = (which==0) ? QSCALE : 1.0f;
    #pragma unroll
    for (int m=0;m<4;m++)
      #pragma unroll
      for (int n=0;n<4;n++){
        int gn = n0 + wc*64 + n*16 + lr;
        float bv = bias[gn];
        int cn = gn - which*768;
        int h = cn >> 6, d = cn & 63;
        int gm0 = m0 + wr*64 + m*16 + lg*4;
        int b = gm0 >> 11, t0 = gm0 & 2047;
        if (which < 2){
          #pragma unroll
          for (int r=0;r<4;r++)
            dst[(size_t)((b*12 + h)*2048 + t0 + r)*64 + d] = f2bf((acc[m][n][r] + bv)*sc);
        } else {
          uint2 o;
          o.x = cvtpk_bf16(acc[m][n][0]+bv, acc[m][n][1]+bv);
          o.y = cvtpk_bf16(acc[m][n][2]+bv, acc[m][n][3]+bv);
          *(uint2*)&vo[((size_t)((b*12 + h)*64 + d))*2048 + t0] = o;
        }
      }
  }
}

// ---------------- causal flash attention: barrier-free, LDS-free ----------------
// 1 wave per block (64 thr), 16 q-rows per wave. grid (128, B*H), heavy tiles first.
// K/V MFMA fragments read DIRECTLY from global (L2-resident: 256KB per head).
// Swapped QK^T (mfma(K,Q)): per-lane softmax state, q = lane&15.
// K-frag addresses pi-permuted so the 16 in-register scores ARE the PV B-frag slices.
// K double-buffered in regs (next tile prefetched); V issued at iter top, consumed
// after QK+softmax (~300cy later) so L2 latency is hidden.
__global__ __launch_bounds__(64) void attn_k(
    const u16* __restrict__ qp, const u16* __restrict__ kp,
    const u16* __restrict__ vtp, u16* __restrict__ yp)
{
  const int bh = blockIdx.y;
  const int wt = 127 - (int)blockIdx.x;     // heavy first
  const int q0w = wt * 16;
  const int b = bh / 12, h = bh - b*12;
  const size_t base = (size_t)bh * 131072;  // 2048*64
  const int lane = threadIdx.x;
  const int lr = lane & 15, lg = lane >> 4;
  const int qg = q0w + lr;

  bf16x8 qf[2];
  #pragma unroll
  for (int kb=0;kb<2;kb++)
    qf[kb] = *(const bf16x8*)&qp[base + (size_t)qg*64 + kb*32 + lg*8];

  f32x4 yacc[4] = {};
  float m2 = -1e30f, l = 0.f;
  const int nt = (wt >> 2) + 1;

  // per-lane fragment offsets (elements)
  int kofs[4];
  #pragma unroll
  for (int nb=0;nb<4;nb++)
    kofs[nb] = ((nb&1)*32 + (lr>>2)*8 + (nb>>1)*4 + (lr&3))*64 + lg*8;
  size_t vofs[4];
  #pragma unroll
  for (int n=0;n<4;n++)
    vofs[n] = base + (size_t)(n*16+lr)*2048 + lg*8;

  bf16x8 kA[8], kB[8], vf[8];

  auto loadK = [&](bf16x8* kf, int t){
    const size_t tb = base + (size_t)t*4096;   // (t*64 keys)*64 d
    #pragma unroll
    for (int nb=0;nb<4;nb++){
      #pragma unroll
      for (int kb=0;kb<2;kb++)
        kf[nb*2+kb] = *(const bf16x8*)&kp[tb + (size_t)(kofs[nb] + kb*32)];
    }
  };
  auto loadV = [&](int t){
    #pragma unroll
    for (int n=0;n<4;n++){
      #pragma unroll
      for (int kc=0;kc<2;kc++)
        vf[n*2+kc] = *(const bf16x8*)&vtp[vofs[n] + t*64 + kc*32];
    }
  };

  auto compute = [&](int t, const bf16x8* kf){
    const int k0 = t*64;
    const int nbmin[4] = {0, 32, 4, 36};
    f32x4 s[4] = {};
    #pragma unroll
    for (int nb=0;nb<4;nb++){
      if (k0 + nbmin[nb] <= q0w + 15){     // wave-uniform: sub-tile has live keys
        #pragma unroll
        for (int kb=0;kb<2;kb++)
          s[nb] = mfma_bf16(kf[nb*2+kb], qf[kb], s[nb]);
      }
    }
    if (k0 + 63 > q0w){                    // diagonal tile: per-element causal mask
      #pragma unroll
      for (int nb=0;nb<4;nb++){
        int kb0 = k0 + (nb&1)*32 + ((nb>>1)&1)*4 + lg*8;
        #pragma unroll
        for (int r=0;r<4;r++)
          if (kb0 + r > qg) s[nb][r] = -1e30f;
      }
    }
    float tmax = s[0][0];
    #pragma unroll
    for (int nb=0;nb<4;nb++){
      #pragma unroll
      for (int r=0;r<4;r++) tmax = fmaxf(tmax, s[nb][r]);
    }
    tmax = fmaxf(tmax, __shfl_xor(tmax, 16));
    tmax = fmaxf(tmax, __shfl_xor(tmax, 32));
    if (!__all(tmax <= m2 + 11.5f)){       // deferred rescale (T13), rare
      float m2n = fmaxf(m2, tmax);
      float al = fexp2(m2 - m2n);
      l *= al;
      #pragma unroll
      for (int n=0;n<4;n++) yacc[n] *= al;
      m2 = m2n;
    }
    float lsum = 0.f;
    #pragma unroll
    for (int nb=0;nb<4;nb++){
      if (k0 + nbmin[nb] <= q0w + 15){
        #pragma unroll
        for (int r=0;r<4;r++){
          float p = fexp2(s[nb][r] - m2);
          s[nb][r] = p;
          lsum += p;
        }
      } else {
        #pragma unroll
        for (int r=0;r<4;r++) s[nb][r] = 0.f;
      }
    }
    l += lsum;
    uint32_t pk8[8];
    #pragma unroll
    for (int nb=0;nb<4;nb++){
      pk8[nb*2]   = cvtpk_bf16(s[nb][0], s[nb][1]);
      pk8[nb*2+1] = cvtpk_bf16(s[nb][2], s[nb][3]);
    }
    #pragma unroll
    for (int kc=0;kc<2;kc++){
      union { uint32_t u[4]; bf16x8 v; } pb;
      pb.u[0] = pk8[kc*2];   pb.u[1] = pk8[kc*2+1];
      pb.u[2] = pk8[kc*2+4]; pb.u[3] = pk8[kc*2+5];
      #pragma unroll
      for (int n=0;n<4;n++)
        yacc[n] = mfma_bf16(vf[n*2+kc], pb.v, yacc[n]);
    }
  };

  loadK(kA, 0);
  int t = 0;
  for (;;){
    loadV(t);
    if (t+1 < nt) loadK(kB, t+1);
    compute(t, kA);
    if (++t >= nt) break;
    loadV(t);
    if (t+1 < nt) loadK(kA, t+1);
    compute(t, kB);
    if (++t >= nt) break;
  }

  l += __shfl_xor(l, 16);
  l += __shfl_xor(l, 32);
  float inv = 1.0f / l;
  #pragma unroll
  for (int n=0;n<4;n++){
    uint2 o;
    o.x = cvtpk_bf16(yacc[n][0]*inv, yacc[n][1]*inv);
    o.y = cvtpk_bf16(yacc[n][2]*inv, yacc[n][3]*inv);
    *(uint2*)&yp[(size_t)(b*2048 + qg)*768 + h*64 + n*16 + lg*4] = o;
  }
}

extern "C" void kernel_launch(void* const* d_in, const int* in_sizes, int n_in,
                              void* d_out, int out_size, void* d_ws, size_t ws_size,
                              hipStream_t stream)
{
  const float* x  = (const float*)d_in[0];   // [2,2048,768]
  const float* Wa = (const float*)d_in[1];   // [768,2304]
  const float* ba = (const float*)d_in[2];   // [2304]
  const float* Wp = (const float*)d_in[3];   // [768,768]
  const float* bp = (const float*)d_in[4];   // [768]
  float* out = (float*)d_out;                // [2,2048,768] fp32
  char* ws = (char*)d_ws;
  u16* xb  = (u16*)(ws + 0);         // x bf16          [4096][768]
  u16* wt  = (u16*)(ws + 6291456);   // W_attn^T bf16   [2304][768]
  u16* wpt = (u16*)(ws + 9830400);   // W_proj^T bf16   [768][768]
  u16* qb  = (u16*)(ws + 11010048);  // q bf16 (scaled) [24][2048][64]
  u16* kb  = (u16*)(ws + 17301504);  // k bf16          [24][2048][64]
  u16* vtb = (u16*)(ws + 23592960);  // v^T bf16        [24][64][2048]
  u16* yb  = (u16*)(ws + 29884416);  // attn out bf16   [4096][768]

  cast_x_k<<<3072, 256, 0, stream>>>(x, xb, 786432);
  transpose_cast_k<<<dim3(36,12), 256, 0, stream>>>(Wa, wt, 768, 2304);
  transpose_cast_k<<<dim3(12,12), 256, 0, stream>>>(Wp, wpt, 768, 768);
  gemm_bf16_k<<<dim3(18,32), 256, 0, stream>>>(xb, wt, 4096, 2304, 768, ba, 1,
                                               qb, kb, vtb, nullptr);
  attn_k<<<dim3(128,24), 64, 0, stream>>>(qb, kb, vtb, yb);
  gemm_bf16_k<<<dim3(6,32), 256, 0, stream>>>(yb, wpt, 4096, 768, 768, bp, 0,
                                              nullptr, nullptr, nullptr, out);
}

// Round 4
// 190.404 us; speedup vs baseline: 1.0649x; 1.0649x over previous
//
#include <hip/hip_runtime.h>
#include <stdint.h>

typedef unsigned short u16;
typedef __attribute__((ext_vector_type(8))) short bf16x8;
typedef __attribute__((ext_vector_type(4))) float f32x4;

__device__ __forceinline__ u16 f2bf(float f){
  union { float f; uint32_t u; } v; v.f = f;
  uint32_t u = v.u;
  u += 0x7FFFu + ((u >> 16) & 1u);
  return (u16)(u >> 16);
}

__device__ __forceinline__ float fexp2(float x){
#if __has_builtin(__builtin_amdgcn_exp2f)
  return __builtin_amdgcn_exp2f(x);
#else
  return exp2f(x);
#endif
}

__device__ __forceinline__ uint32_t cvtpk_bf16(float lo, float hi){
  uint32_t d;
  asm("v_cvt_pk_bf16_f32 %0, %1, %2" : "=v"(d) : "v"(lo), "v"(hi));
  return d;
}

__device__ __forceinline__ f32x4 mfma_bf16(bf16x8 a, bf16x8 b, f32x4 c){
  return __builtin_amdgcn_mfma_f32_16x16x32_bf16(a, b, c, 0, 0, 0);
}

// 0.125 (1/sqrt(64)) * log2(e) -- folded into Q at the QKV epilogue
#define QSCALE 0.1803368801111244f

// ---------------- cast x (fp32 -> bf16), 4 elems/thread ----------------
__global__ __launch_bounds__(256) void cast_x_k(const float* __restrict__ x,
                                                u16* __restrict__ xb, int n4){
  int i = blockIdx.x*256 + threadIdx.x;
  if (i >= n4) return;
  float4 v = reinterpret_cast<const float4*>(x)[i];
  uint2 o;
  o.x = (uint32_t)f2bf(v.x) | ((uint32_t)f2bf(v.y) << 16);
  o.y = (uint32_t)f2bf(v.z) | ((uint32_t)f2bf(v.w) << 16);
  reinterpret_cast<uint2*>(xb)[i] = o;
}

// ---------------- transpose+cast: fp32 [R][C] -> bf16 [C][R] ----------------
__global__ __launch_bounds__(256) void transpose_cast_k(const float* __restrict__ in,
                                                        u16* __restrict__ out,
                                                        int R, int C){
  __shared__ u16 tile[64][66];
  int c0 = blockIdx.x*64, r0 = blockIdx.y*64;
  int tc = threadIdx.x & 63, t4 = threadIdx.x >> 6;
  #pragma unroll
  for (int i=0;i<16;i++){ int r = t4 + i*4; tile[r][tc] = f2bf(in[(size_t)(r0+r)*C + c0 + tc]); }
  __syncthreads();
  #pragma unroll
  for (int i=0;i<16;i++){ int cc = t4 + i*4; out[(size_t)(c0+cc)*R + r0 + tc] = tile[tc][cc]; }
}

// ---------------- bf16 MFMA GEMM: C[M][N] = A[M][K] * Bt[N][K]^T + bias ----------------
// mode 0: fp32 out to fo.
// mode 1: scatter bf16: q (pre-scaled) and k into [B*H][T][64]; v written TRANSPOSED
//         into [B*H][64][T].
#define LDP 40   // padded LDS row stride (shorts)

__global__ __launch_bounds__(256) void gemm_bf16_k(
    const u16* __restrict__ A, const u16* __restrict__ Bt,
    int M, int N, int K, const float* __restrict__ bias, int mode,
    u16* __restrict__ qo, u16* __restrict__ ko, u16* __restrict__ vo,
    float* __restrict__ fo)
{
  __shared__ u16 As[128*LDP];
  __shared__ u16 Bs[128*LDP];
  const int m0 = blockIdx.y*128, n0 = blockIdx.x*128;
  const int tid = threadIdx.x, lane = tid & 63, wid = tid >> 6;
  const int lr = lane & 15, lg = lane >> 4;
  const int wr = wid >> 1, wc = wid & 1;
  f32x4 acc[4][4] = {};
  const int nk = K >> 5;
  for (int kk = 0; kk < nk; ++kk){
    #pragma unroll
    for (int s = 0; s < 2; ++s){
      int ci = tid + 256*s;
      int row = ci >> 2, ch = ci & 3;
      *(uint4*)&As[row*LDP + ch*8] = *(const uint4*)&A[(size_t)(m0+row)*K + kk*32 + ch*8];
      *(uint4*)&Bs[row*LDP + ch*8] = *(const uint4*)&Bt[(size_t)(n0+row)*K + kk*32 + ch*8];
    }
    __syncthreads();
    bf16x8 af[4], bfr[4];
    #pragma unroll
    for (int m=0;m<4;m++) af[m] = *(const bf16x8*)&As[(wr*64 + m*16 + lr)*LDP + lg*8];
    #pragma unroll
    for (int n=0;n<4;n++) bfr[n] = *(const bf16x8*)&Bs[(wc*64 + n*16 + lr)*LDP + lg*8];
    #pragma unroll
    for (int m=0;m<4;m++)
      #pragma unroll
      for (int n=0;n<4;n++)
        acc[m][n] = mfma_bf16(af[m], bfr[n], acc[m][n]);
    __syncthreads();
  }
  if (mode == 0){
    #pragma unroll
    for (int m=0;m<4;m++)
      #pragma unroll
      for (int n=0;n<4;n++){
        int gn = n0 + wc*64 + n*16 + lr;
        float bv = bias[gn];
        #pragma unroll
        for (int r=0;r<4;r++){
          int gm = m0 + wr*64 + m*16 + lg*4 + r;
          fo[(size_t)gm*N + gn] = acc[m][n][r] + bv;
        }
      }
  } else {
    int which = n0 / 768;               // 0=q 1=k 2=v, uniform per block
    u16* dst = (which==0) ? qo : ko;
    float sc = (which==0) ? QSCALE : 1.0f;
    #pragma unroll
    for (int m=0;m<4;m++)
      #pragma unroll
      for (int n=0;n<4;n++){
        int gn = n0 + wc*64 + n*16 + lr;
        float bv = bias[gn];
        int cn = gn - which*768;
        int h = cn >> 6, d = cn & 63;
        int gm0 = m0 + wr*64 + m*16 + lg*4;
        int b = gm0 >> 11, t0 = gm0 & 2047;
        if (which < 2){
          #pragma unroll
          for (int r=0;r<4;r++)
            dst[(size_t)((b*12 + h)*2048 + t0 + r)*64 + d] = f2bf((acc[m][n][r] + bv)*sc);
        } else {
          uint2 o;
          o.x = cvtpk_bf16(acc[m][n][0]+bv, acc[m][n][1]+bv);
          o.y = cvtpk_bf16(acc[m][n][2]+bv, acc[m][n][3]+bv);
          *(uint2*)&vo[((size_t)((b*12 + h)*64 + d))*2048 + t0] = o;
        }
      }
  }
}

// ---------------- causal flash attention: split-K, 4 waves per q-tile ----------------
// Block = 256 thr = one 16-row q-tile; wave w handles key-tiles t = w, w+4, ...
// K/V fragments read directly from global (L2-resident). Swapped QK^T (mfma(K,Q)):
// per-lane softmax state. FIXED shift m2=8 keeps exp2 directly after the MFMA (no
// max-dependency on the critical chain); the max check runs concurrently and the
// (never-taken in practice) fixup rescales yacc AFTER PV -- mathematically exact.
// Partials merged once per block through LDS (single barrier).
__global__ __launch_bounds__(256) void attn_k(
    const u16* __restrict__ qp, const u16* __restrict__ kp,
    const u16* __restrict__ vtp, u16* __restrict__ yp)
{
  __shared__ f32x4 yl[16][64];        // [w*4+n][lane]
  __shared__ float ml[4][16];
  __shared__ float ll[4][16];
  const int bh = blockIdx.y;
  const int qt = 127 - (int)blockIdx.x;     // heavy first
  const int q0w = qt * 16;
  const int b = bh / 12, h = bh - b*12;
  const size_t base = (size_t)bh * 131072;  // 2048*64
  const int tid = threadIdx.x, lane = tid & 63, wid = tid >> 6;
  const int lr = lane & 15, lg = lane >> 4;
  const int qg = q0w + lr;

  bf16x8 qf[2];
  #pragma unroll
  for (int kb=0;kb<2;kb++)
    qf[kb] = *(const bf16x8*)&qp[base + (size_t)qg*64 + kb*32 + lg*8];

  f32x4 yacc[4] = {};
  float m2 = 8.f, l = 0.f;
  const int nt = (qt >> 2) + 1;

  int kofs[4];
  #pragma unroll
  for (int nb=0;nb<4;nb++)
    kofs[nb] = ((nb&1)*32 + (lr>>2)*8 + (nb>>1)*4 + (lr&3))*64 + lg*8;
  size_t vofs[4];
  #pragma unroll
  for (int n=0;n<4;n++)
    vofs[n] = base + (size_t)(n*16+lr)*2048 + lg*8;

  bf16x8 kA[8], kB[8], vf[8];

  auto loadK = [&](bf16x8 (&kf)[8], int t){
    const size_t tb = base + (size_t)t*4096;
    #pragma unroll
    for (int nb=0;nb<4;nb++){
      #pragma unroll
      for (int kb=0;kb<2;kb++)
        kf[nb*2+kb] = *(const bf16x8*)&kp[tb + (size_t)(kofs[nb] + kb*32)];
    }
  };
  auto loadV = [&](int t){
    #pragma unroll
    for (int n=0;n<4;n++){
      #pragma unroll
      for (int kc=0;kc<2;kc++)
        vf[n*2+kc] = *(const bf16x8*)&vtp[vofs[n] + t*64 + kc*32];
    }
  };

  auto compute = [&](int t, const bf16x8 (&kf)[8]){
    const int k0 = t*64;
    const int nbmin[4] = {0, 32, 4, 36};
    f32x4 s[4] = {};
    #pragma unroll
    for (int nb=0;nb<4;nb++){
      if (k0 + nbmin[nb] <= q0w + 15){
        #pragma unroll
        for (int kb=0;kb<2;kb++)
          s[nb] = mfma_bf16(kf[nb*2+kb], qf[kb], s[nb]);
      }
    }
    if (k0 + 63 > q0w){                    // diagonal tile: causal mask
      #pragma unroll
      for (int nb=0;nb<4;nb++){
        int kb0 = k0 + (nb&1)*32 + ((nb>>1)&1)*4 + lg*8;
        #pragma unroll
        for (int r=0;r<4;r++)
          if (kb0 + r > qg) s[nb][r] = -1e30f;
      }
    }
    // p = 2^(s - m2) straight off the MFMA output (no max on the chain)
    float lsum = 0.f;
    #pragma unroll
    for (int nb=0;nb<4;nb++){
      if (k0 + nbmin[nb] <= q0w + 15){
        #pragma unroll
        for (int r=0;r<4;r++){
          float p = fexp2(s[nb][r] - m2);
          s[nb][r] = p;
          lsum += p;
        }
      } else {
        #pragma unroll
        for (int r=0;r<4;r++) s[nb][r] = 0.f;
      }
    }
    // pack + PV immediately (critical chain)
    uint32_t pk8[8];
    #pragma unroll
    for (int nb=0;nb<4;nb++){
      pk8[nb*2]   = cvtpk_bf16(s[nb][0], s[nb][1]);
      pk8[nb*2+1] = cvtpk_bf16(s[nb][2], s[nb][3]);
    }
    #pragma unroll
    for (int kc=0;kc<2;kc++){
      union { uint32_t u[4]; bf16x8 v; } pb;
      pb.u[0] = pk8[kc*2];   pb.u[1] = pk8[kc*2+1];
      pb.u[2] = pk8[kc*2+4]; pb.u[3] = pk8[kc*2+5];
      #pragma unroll
      for (int n=0;n<4;n++)
        yacc[n] = mfma_bf16(vf[n*2+kc], pb.v, yacc[n]);
    }
    l += lsum;
    // off-chain overflow guard: max of p's, threshold 2^11.5; fixup is exact
    float pmax = s[0][0];
    #pragma unroll
    for (int nb=0;nb<4;nb++){
      #pragma unroll
      for (int r=0;r<4;r++) pmax = fmaxf(pmax, s[nb][r]);
    }
    pmax = fmaxf(pmax, __shfl_xor(pmax, 16));
    pmax = fmaxf(pmax, __shfl_xor(pmax, 32));
    if (!__all(pmax <= 2896.31f)){         // rare: rescale AFTER PV (exact)
      float m2n = fmaxf(m2, m2 + __log2f(pmax));
      float al = fexp2(m2 - m2n);
      l *= al;
      #pragma unroll
      for (int n=0;n<4;n++) yacc[n] *= al;
      m2 = m2n;
    }
  };

  // wave wid processes tiles t = wid, wid+4, ... (register double-buffered K)
  int t = wid;
  if (t < nt){
    loadK(kA, t);
    for (;;){
      loadV(t);
      if (t+4 < nt) loadK(kB, t+4);
      compute(t, kA);
      t += 4;
      if (t >= nt) break;
      loadV(t);
      if (t+4 < nt) loadK(kA, t+4);
      compute(t, kB);
      t += 4;
      if (t >= nt) break;
    }
  }

  // per-wave l: sum across the 4 lg-lanes of each q-row
  l += __shfl_xor(l, 16);
  l += __shfl_xor(l, 32);

  // publish partials
  #pragma unroll
  for (int n=0;n<4;n++) yl[wid*4+n][lane] = yacc[n];
  if (lg == 0){ ml[wid][lr] = m2; ll[wid][lr] = l; }
  __syncthreads();

  // merge: wave `wid` produces output slice n = wid
  float m0 = ml[0][lr], m1 = ml[1][lr], m2r = ml[2][lr], m3 = ml[3][lr];
  float ms = fmaxf(fmaxf(m0, m1), fmaxf(m2r, m3));
  float a0 = fexp2(m0 - ms), a1 = fexp2(m1 - ms),
        a2 = fexp2(m2r - ms), a3 = fexp2(m3 - ms);
  float Ls = a0*ll[0][lr] + a1*ll[1][lr] + a2*ll[2][lr] + a3*ll[3][lr];
  f32x4 y0 = yl[0*4+wid][lane], y1 = yl[1*4+wid][lane],
        y2 = yl[2*4+wid][lane], y3 = yl[3*4+wid][lane];
  f32x4 ys;
  #pragma unroll
  for (int r=0;r<4;r++) ys[r] = a0*y0[r] + a1*y1[r] + a2*y2[r] + a3*y3[r];
  float inv = 1.0f / Ls;
  uint2 o;
  o.x = cvtpk_bf16(ys[0]*inv, ys[1]*inv);
  o.y = cvtpk_bf16(ys[2]*inv, ys[3]*inv);
  *(uint2*)&yp[(size_t)(b*2048 + qg)*768 + h*64 + wid*16 + lg*4] = o;
}

extern "C" void kernel_launch(void* const* d_in, const int* in_sizes, int n_in,
                              void* d_out, int out_size, void* d_ws, size_t ws_size,
                              hipStream_t stream)
{
  const float* x  = (const float*)d_in[0];   // [2,2048,768]
  const float* Wa = (const float*)d_in[1];   // [768,2304]
  const float* ba = (const float*)d_in[2];   // [2304]
  const float* Wp = (const float*)d_in[3];   // [768,768]
  const float* bp = (const float*)d_in[4];   // [768]
  float* out = (float*)d_out;                // [2,2048,768] fp32
  char* ws = (char*)d_ws;
  u16* xb  = (u16*)(ws + 0);         // x bf16          [4096][768]
  u16* wt  = (u16*)(ws + 6291456);   // W_attn^T bf16   [2304][768]
  u16* wpt = (u16*)(ws + 9830400);   // W_proj^T bf16   [768][768]
  u16* qb  = (u16*)(ws + 11010048);  // q bf16 (scaled) [24][2048][64]
  u16* kb  = (u16*)(ws + 17301504);  // k bf16          [24][2048][64]
  u16* vtb = (u16*)(ws + 23592960);  // v^T bf16        [24][64][2048]
  u16* yb  = (u16*)(ws + 29884416);  // attn out bf16   [4096][768]

  cast_x_k<<<3072, 256, 0, stream>>>(x, xb, 786432);
  transpose_cast_k<<<dim3(36,12), 256, 0, stream>>>(Wa, wt, 768, 2304);
  transpose_cast_k<<<dim3(12,12), 256, 0, stream>>>(Wp, wpt, 768, 768);
  gemm_bf16_k<<<dim3(18,32), 256, 0, stream>>>(xb, wt, 4096, 2304, 768, ba, 1,
                                               qb, kb, vtb, nullptr);
  attn_k<<<dim3(128,24), 256, 0, stream>>>(qb, kb, vtb, yb);
  gemm_bf16_k<<<dim3(6,32), 256, 0, stream>>>(yb, wpt, 4096, 768, 768, bp, 0,
                                              nullptr, nullptr, nullptr, out);
}

// Round 5
// 163.681 us; speedup vs baseline: 1.2388x; 1.1633x over previous
//
#include <hip/hip_runtime.h>
#include <stdint.h>

typedef unsigned short u16;
typedef __attribute__((ext_vector_type(8))) short bf16x8;
typedef __attribute__((ext_vector_type(4))) float f32x4;

__device__ __forceinline__ u16 f2bf(float f){
  union { float f; uint32_t u; } v; v.f = f;
  uint32_t u = v.u;
  u += 0x7FFFu + ((u >> 16) & 1u);
  return (u16)(u >> 16);
}

__device__ __forceinline__ float fexp2(float x){
#if __has_builtin(__builtin_amdgcn_exp2f)
  return __builtin_amdgcn_exp2f(x);
#else
  return exp2f(x);
#endif
}

__device__ __forceinline__ uint32_t cvtpk_bf16(float lo, float hi){
  uint32_t d;
  asm("v_cvt_pk_bf16_f32 %0, %1, %2" : "=v"(d) : "v"(lo), "v"(hi));
  return d;
}

__device__ __forceinline__ f32x4 mfma_bf16(bf16x8 a, bf16x8 b, f32x4 c){
  return __builtin_amdgcn_mfma_f32_16x16x32_bf16(a, b, c, 0, 0, 0);
}

// 0.125 (1/sqrt(64)) * log2(e) -- folded into Q at the QKV epilogue
#define QSCALE 0.1803368801111244f

// ---------------- cast x (fp32 -> bf16), 4 elems/thread ----------------
__global__ __launch_bounds__(256) void cast_x_k(const float* __restrict__ x,
                                                u16* __restrict__ xb, int n4){
  int i = blockIdx.x*256 + threadIdx.x;
  if (i >= n4) return;
  float4 v = reinterpret_cast<const float4*>(x)[i];
  uint2 o;
  o.x = (uint32_t)f2bf(v.x) | ((uint32_t)f2bf(v.y) << 16);
  o.y = (uint32_t)f2bf(v.z) | ((uint32_t)f2bf(v.w) << 16);
  reinterpret_cast<uint2*>(xb)[i] = o;
}

// ---------------- transpose+cast: fp32 [R][C] -> bf16 [C][R] ----------------
__global__ __launch_bounds__(256) void transpose_cast_k(const float* __restrict__ in,
                                                        u16* __restrict__ out,
                                                        int R, int C){
  __shared__ u16 tile[64][66];
  int c0 = blockIdx.x*64, r0 = blockIdx.y*64;
  int tc = threadIdx.x & 63, t4 = threadIdx.x >> 6;
  #pragma unroll
  for (int i=0;i<16;i++){ int r = t4 + i*4; tile[r][tc] = f2bf(in[(size_t)(r0+r)*C + c0 + tc]); }
  __syncthreads();
  #pragma unroll
  for (int i=0;i<16;i++){ int cc = t4 + i*4; out[(size_t)(c0+cc)*R + r0 + tc] = tile[tc][cc]; }
}

// ---------------- bf16 MFMA GEMM: C[M][N] = A[M][K] * Bt[N][K]^T + bias ----------------
// mode 0: fp32 out to fo.
// mode 1: scatter bf16: q (pre-scaled) and k into [B*H][T][64]; v written TRANSPOSED
//         into [B*H][64][T].
#define LDP 40   // padded LDS row stride (shorts)

__global__ __launch_bounds__(256) void gemm_bf16_k(
    const u16* __restrict__ A, const u16* __restrict__ Bt,
    int M, int N, int K, const float* __restrict__ bias, int mode,
    u16* __restrict__ qo, u16* __restrict__ ko, u16* __restrict__ vo,
    float* __restrict__ fo)
{
  __shared__ u16 As[128*LDP];
  __shared__ u16 Bs[128*LDP];
  const int m0 = blockIdx.y*128, n0 = blockIdx.x*128;
  const int tid = threadIdx.x, lane = tid & 63, wid = tid >> 6;
  const int lr = lane & 15, lg = lane >> 4;
  const int wr = wid >> 1, wc = wid & 1;
  f32x4 acc[4][4] = {};
  const int nk = K >> 5;
  for (int kk = 0; kk < nk; ++kk){
    #pragma unroll
    for (int s = 0; s < 2; ++s){
      int ci = tid + 256*s;
      int row = ci >> 2, ch = ci & 3;
      *(uint4*)&As[row*LDP + ch*8] = *(const uint4*)&A[(size_t)(m0+row)*K + kk*32 + ch*8];
      *(uint4*)&Bs[row*LDP + ch*8] = *(const uint4*)&Bt[(size_t)(n0+row)*K + kk*32 + ch*8];
    }
    __syncthreads();
    bf16x8 af[4], bfr[4];
    #pragma unroll
    for (int m=0;m<4;m++) af[m] = *(const bf16x8*)&As[(wr*64 + m*16 + lr)*LDP + lg*8];
    #pragma unroll
    for (int n=0;n<4;n++) bfr[n] = *(const bf16x8*)&Bs[(wc*64 + n*16 + lr)*LDP + lg*8];
    #pragma unroll
    for (int m=0;m<4;m++)
      #pragma unroll
      for (int n=0;n<4;n++)
        acc[m][n] = mfma_bf16(af[m], bfr[n], acc[m][n]);
    __syncthreads();
  }
  if (mode == 0){
    #pragma unroll
    for (int m=0;m<4;m++)
      #pragma unroll
      for (int n=0;n<4;n++){
        int gn = n0 + wc*64 + n*16 + lr;
        float bv = bias[gn];
        #pragma unroll
        for (int r=0;r<4;r++){
          int gm = m0 + wr*64 + m*16 + lg*4 + r;
          fo[(size_t)gm*N + gn] = acc[m][n][r] + bv;
        }
      }
  } else {
    int which = n0 / 768;               // 0=q 1=k 2=v, uniform per block
    u16* dst = (which==0) ? qo : ko;
    float sc = (which==0) ? QSCALE : 1.0f;
    #pragma unroll
    for (int m=0;m<4;m++)
      #pragma unroll
      for (int n=0;n<4;n++){
        int gn = n0 + wc*64 + n*16 + lr;
        float bv = bias[gn];
        int cn = gn - which*768;
        int h = cn >> 6, d = cn & 63;
        int gm0 = m0 + wr*64 + m*16 + lg*4;
        int b = gm0 >> 11, t0 = gm0 & 2047;
        if (which < 2){
          #pragma unroll
          for (int r=0;r<4;r++)
            dst[(size_t)((b*12 + h)*2048 + t0 + r)*64 + d] = f2bf((acc[m][n][r] + bv)*sc);
        } else {
          uint2 o;
          o.x = cvtpk_bf16(acc[m][n][0]+bv, acc[m][n][1]+bv);
          o.y = cvtpk_bf16(acc[m][n][2]+bv, acc[m][n][3]+bv);
          *(uint2*)&vo[((size_t)((b*12 + h)*64 + d))*2048 + t0] = o;
        }
      }
  }
}

// ---------------- causal flash attention: split-K, XCD-pinned heads ----------------
// 1-D grid of 3072 blocks: head = i % 24 (24 == 0 mod 8 => head pinned to XCD h%8,
// 3 heads/XCD => K/V 1.5MB stays L2-resident), qt = 127 - i/24 (global heavy-first).
// Block = 256 thr = one 16-row q-tile; wave w handles key-tiles t = w, w+4, ...
// K AND V fragments double-buffered in regs, prefetched one wave-iter (~600cy) ahead,
// issued BEFORE compute -> load latency fully off the critical chain.
// Swapped QK^T (mfma(K,Q)); FIXED shift m2=8 => exp2 straight off the MFMA; overflow
// guard runs off-chain, (rare) fixup rescales after PV -- exact. One-barrier merge.
__global__ __launch_bounds__(256) void attn_k(
    const u16* __restrict__ qp, const u16* __restrict__ kp,
    const u16* __restrict__ vtp, u16* __restrict__ yp)
{
  __shared__ f32x4 yl[16][64];        // [w*4+n][lane]
  __shared__ float ml[4][16];
  __shared__ float ll[4][16];
  const int i = blockIdx.x;
  const int bh = i % 24;
  const int qt = 127 - (i / 24);            // heavy first, all heads at once
  const int q0w = qt * 16;
  const int b = bh / 12, h = bh - b*12;
  const size_t base = (size_t)bh * 131072;  // 2048*64
  const int tid = threadIdx.x, lane = tid & 63, wid = tid >> 6;
  const int lr = lane & 15, lg = lane >> 4;
  const int qg = q0w + lr;

  bf16x8 qf[2];
  #pragma unroll
  for (int kb=0;kb<2;kb++)
    qf[kb] = *(const bf16x8*)&qp[base + (size_t)qg*64 + kb*32 + lg*8];

  f32x4 yacc[4] = {};
  float m2 = 8.f, l = 0.f;
  const int nt = (qt >> 2) + 1;

  int kofs[4];
  #pragma unroll
  for (int nb=0;nb<4;nb++)
    kofs[nb] = ((nb&1)*32 + (lr>>2)*8 + (nb>>1)*4 + (lr&3))*64 + lg*8;
  size_t vofs[4];
  #pragma unroll
  for (int n=0;n<4;n++)
    vofs[n] = base + (size_t)(n*16+lr)*2048 + lg*8;

  bf16x8 kA[8], kB[8], vA[8], vB[8];

  auto loadK = [&](bf16x8 (&kf)[8], int t){
    const size_t tb = base + (size_t)t*4096;
    #pragma unroll
    for (int nb=0;nb<4;nb++){
      #pragma unroll
      for (int kb=0;kb<2;kb++)
        kf[nb*2+kb] = *(const bf16x8*)&kp[tb + (size_t)(kofs[nb] + kb*32)];
    }
  };
  auto loadV = [&](bf16x8 (&vf)[8], int t){
    #pragma unroll
    for (int n=0;n<4;n++){
      #pragma unroll
      for (int kc=0;kc<2;kc++)
        vf[n*2+kc] = *(const bf16x8*)&vtp[vofs[n] + t*64 + kc*32];
    }
  };

  auto compute = [&](int t, const bf16x8 (&kf)[8], const bf16x8 (&vf)[8]){
    const int k0 = t*64;
    const int nbmin[4] = {0, 32, 4, 36};
    f32x4 s[4] = {};
    #pragma unroll
    for (int nb=0;nb<4;nb++){
      if (k0 + nbmin[nb] <= q0w + 15){
        #pragma unroll
        for (int kb=0;kb<2;kb++)
          s[nb] = mfma_bf16(kf[nb*2+kb], qf[kb], s[nb]);
      }
    }
    if (k0 + 63 > q0w){                    // diagonal tile: causal mask
      #pragma unroll
      for (int nb=0;nb<4;nb++){
        int kb0 = k0 + (nb&1)*32 + ((nb>>1)&1)*4 + lg*8;
        #pragma unroll
        for (int r=0;r<4;r++)
          if (kb0 + r > qg) s[nb][r] = -1e30f;
      }
    }
    // p = 2^(s - m2) straight off the MFMA output (no max on the chain)
    float lsum = 0.f;
    #pragma unroll
    for (int nb=0;nb<4;nb++){
      if (k0 + nbmin[nb] <= q0w + 15){
        #pragma unroll
        for (int r=0;r<4;r++){
          float p = fexp2(s[nb][r] - m2);
          s[nb][r] = p;
          lsum += p;
        }
      } else {
        #pragma unroll
        for (int r=0;r<4;r++) s[nb][r] = 0.f;
      }
    }
    // pack + PV immediately (critical chain)
    uint32_t pk8[8];
    #pragma unroll
    for (int nb=0;nb<4;nb++){
      pk8[nb*2]   = cvtpk_bf16(s[nb][0], s[nb][1]);
      pk8[nb*2+1] = cvtpk_bf16(s[nb][2], s[nb][3]);
    }
    #pragma unroll
    for (int kc=0;kc<2;kc++){
      union { uint32_t u[4]; bf16x8 v; } pb;
      pb.u[0] = pk8[kc*2];   pb.u[1] = pk8[kc*2+1];
      pb.u[2] = pk8[kc*2+4]; pb.u[3] = pk8[kc*2+5];
      #pragma unroll
      for (int n=0;n<4;n++)
        yacc[n] = mfma_bf16(vf[n*2+kc], pb.v, yacc[n]);
    }
    l += lsum;
    // off-chain overflow guard: threshold 2^11.5; fixup AFTER PV (exact)
    float pmax = s[0][0];
    #pragma unroll
    for (int nb=0;nb<4;nb++){
      #pragma unroll
      for (int r=0;r<4;r++) pmax = fmaxf(pmax, s[nb][r]);
    }
    pmax = fmaxf(pmax, __shfl_xor(pmax, 16));
    pmax = fmaxf(pmax, __shfl_xor(pmax, 32));
    if (!__all(pmax <= 2896.31f)){
      float m2n = fmaxf(m2, m2 + __log2f(pmax));
      float al = fexp2(m2 - m2n);
      l *= al;
      #pragma unroll
      for (int n=0;n<4;n++) yacc[n] *= al;
      m2 = m2n;
    }
  };

  // wave wid: tiles t = wid, wid+4, ...; K and V both 1-iter-ahead double-buffered
  int t = wid;
  if (t < nt){
    loadK(kA, t);
    loadV(vA, t);
    for (;;){
      if (t+4 < nt){ loadK(kB, t+4); loadV(vB, t+4); }
      compute(t, kA, vA);
      t += 4;
      if (t >= nt) break;
      if (t+4 < nt){ loadK(kA, t+4); loadV(vA, t+4); }
      compute(t, kB, vB);
      t += 4;
      if (t >= nt) break;
    }
  }

  // per-wave l: sum across the 4 lg-lanes of each q-row
  l += __shfl_xor(l, 16);
  l += __shfl_xor(l, 32);

  // publish partials
  #pragma unroll
  for (int n=0;n<4;n++) yl[wid*4+n][lane] = yacc[n];
  if (lg == 0){ ml[wid][lr] = m2; ll[wid][lr] = l; }
  __syncthreads();

  // merge: wave `wid` produces output slice n = wid
  float m0 = ml[0][lr], m1 = ml[1][lr], m2r = ml[2][lr], m3 = ml[3][lr];
  float ms = fmaxf(fmaxf(m0, m1), fmaxf(m2r, m3));
  float a0 = fexp2(m0 - ms), a1 = fexp2(m1 - ms),
        a2 = fexp2(m2r - ms), a3 = fexp2(m3 - ms);
  float Ls = a0*ll[0][lr] + a1*ll[1][lr] + a2*ll[2][lr] + a3*ll[3][lr];
  f32x4 y0 = yl[0*4+wid][lane], y1 = yl[1*4+wid][lane],
        y2 = yl[2*4+wid][lane], y3 = yl[3*4+wid][lane];
  f32x4 ys;
  #pragma unroll
  for (int r=0;r<4;r++) ys[r] = a0*y0[r] + a1*y1[r] + a2*y2[r] + a3*y3[r];
  float inv = 1.0f / Ls;
  uint2 o;
  o.x = cvtpk_bf16(ys[0]*inv, ys[1]*inv);
  o.y = cvtpk_bf16(ys[2]*inv, ys[3]*inv);
  *(uint2*)&yp[(size_t)(b*2048 + qg)*768 + h*64 + wid*16 + lg*4] = o;
}

extern "C" void kernel_launch(void* const* d_in, const int* in_sizes, int n_in,
                              void* d_out, int out_size, void* d_ws, size_t ws_size,
                              hipStream_t stream)
{
  const float* x  = (const float*)d_in[0];   // [2,2048,768]
  const float* Wa = (const float*)d_in[1];   // [768,2304]
  const float* ba = (const float*)d_in[2];   // [2304]
  const float* Wp = (const float*)d_in[3];   // [768,768]
  const float* bp = (const float*)d_in[4];   // [768]
  float* out = (float*)d_out;                // [2,2048,768] fp32
  char* ws = (char*)d_ws;
  u16* xb  = (u16*)(ws + 0);         // x bf16          [4096][768]
  u16* wt  = (u16*)(ws + 6291456);   // W_attn^T bf16   [2304][768]
  u16* wpt = (u16*)(ws + 9830400);   // W_proj^T bf16   [768][768]
  u16* qb  = (u16*)(ws + 11010048);  // q bf16 (scaled) [24][2048][64]
  u16* kb  = (u16*)(ws + 17301504);  // k bf16          [24][2048][64]
  u16* vtb = (u16*)(ws + 23592960);  // v^T bf16        [24][64][2048]
  u16* yb  = (u16*)(ws + 29884416);  // attn out bf16   [4096][768]

  cast_x_k<<<3072, 256, 0, stream>>>(x, xb, 786432);
  transpose_cast_k<<<dim3(36,12), 256, 0, stream>>>(Wa, wt, 768, 2304);
  transpose_cast_k<<<dim3(12,12), 256, 0, stream>>>(Wp, wpt, 768, 768);
  gemm_bf16_k<<<dim3(18,32), 256, 0, stream>>>(xb, wt, 4096, 2304, 768, ba, 1,
                                               qb, kb, vtb, nullptr);
  attn_k<<<3072, 256, 0, stream>>>(qb, kb, vtb, yb);
  gemm_bf16_k<<<dim3(6,32), 256, 0, stream>>>(yb, wpt, 4096, 768, 768, bp, 0,
                                              nullptr, nullptr, nullptr, out);
}